// Round 4
// baseline (269.756 us; speedup 1.0000x reference)
//
#include <hip/hip_runtime.h>
#include <hip/hip_bf16.h>

#define N_NODES 100000
#define N_EDGES 1000000
#define EPS 1e-5f
#define SLOPE 0.1f

typedef __attribute__((ext_vector_type(8))) short short8;
typedef __attribute__((ext_vector_type(4))) float f32x4;
typedef __attribute__((ext_vector_type(2))) float f32x2;

#define MFMA16(a, b, c) __builtin_amdgcn_mfma_f32_16x16x32_bf16(a, b, c, 0, 0, 0)

__device__ __forceinline__ float lrelu(float v) { return v > 0.f ? v : SLOPE * v; }

__device__ __forceinline__ unsigned short f2bf(float f) {
  __hip_bfloat16 h = __float2bfloat16(f);
  return __builtin_bit_cast(unsigned short, h);
}
__device__ __forceinline__ unsigned pk2(float lo, float hi) {
  return (unsigned)f2bf(lo) | ((unsigned)f2bf(hi) << 16);
}
__device__ __forceinline__ float blo(unsigned u) { return __uint_as_float(u << 16); }
__device__ __forceinline__ float bhi(unsigned u) { return __uint_as_float(u & 0xffff0000u); }

__device__ __forceinline__ short8 mk_frag8(const float v[8]) {
  uint4 u;
  u.x = pk2(v[0], v[1]);
  u.y = pk2(v[2], v[3]);
  u.z = pk2(v[4], v[5]);
  u.w = pk2(v[6], v[7]);
  return __builtin_bit_cast(short8, u);
}

#if __has_builtin(__builtin_amdgcn_global_atomic_fadd_v2f32)
#define HAVE_PK2_ATOMIC 1
typedef __attribute__((address_space(1))) f32x2 gf32x2;
__device__ __forceinline__ void atomic_pk2(float* p, float a, float b) {
  f32x2 v = {a, b};
  __builtin_amdgcn_global_atomic_fadd_v2f32((gf32x2*)(unsigned long long)p, v);
}
#else
#define HAVE_PK2_ATOMIC 0
#endif

// ============================================================================
// Fused node MLP: x_t = (lrelu(x@W1n + b1n))@W2n + b2n, stored bf16 [N,64].
// ============================================================================
__global__ __launch_bounds__(256) void node_mfma(const float* __restrict__ x,
                                                 const float* __restrict__ W1n,
                                                 const float* __restrict__ b1n,
                                                 const float* __restrict__ W2n,
                                                 const float* __restrict__ b2n,
                                                 __hip_bfloat16* __restrict__ xt) {
  const int lane = threadIdx.x & 63;
  const int lo = lane & 15;
  const int G = lane >> 4;
  const int wid = (blockIdx.x * blockDim.x + threadIdx.x) >> 6;
  const int nw = (gridDim.x * blockDim.x) >> 6;

  short8 A1[8][2];
#pragma unroll
  for (int t = 0; t < 8; ++t)
#pragma unroll
    for (int kt = 0; kt < 2; ++kt) {
      float v[8];
#pragma unroll
      for (int j = 0; j < 8; ++j) v[j] = W1n[(kt * 32 + G * 8 + j) * 128 + t * 16 + lo];
      A1[t][kt] = mk_frag8(v);
    }
  short8 A2[4][4];
#pragma unroll
  for (int ct = 0; ct < 4; ++ct)
#pragma unroll
    for (int kt = 0; kt < 4; ++kt) {
      float v[8];
#pragma unroll
      for (int j = 0; j < 8; ++j) v[j] = W2n[(kt * 32 + G * 8 + j) * 64 + ct * 16 + lo];
      A2[ct][kt] = mk_frag8(v);
    }
  const f32x4 zero = {0.f, 0.f, 0.f, 0.f};

  for (int tile = wid; tile < N_NODES / 16; tile += nw) {
    const int n0 = tile * 16;
    short8 B1[2];
#pragma unroll
    for (int kt = 0; kt < 2; ++kt) {
      const float* p = &x[(size_t)(n0 + lo) * 64 + kt * 32 + G * 8];
      float4 q0 = *(const float4*)p;
      float4 q1 = *(const float4*)(p + 4);
      float v[8] = {q0.x, q0.y, q0.z, q0.w, q1.x, q1.y, q1.z, q1.w};
      B1[kt] = mk_frag8(v);
    }
    unsigned P[8][2];
#pragma unroll
    for (int t = 0; t < 8; ++t) {
      f32x4 d = MFMA16(A1[t][0], B1[0], zero);
      d = MFMA16(A1[t][1], B1[1], d);
      const float4 bv = *(const float4*)&b1n[t * 16 + G * 4];
      P[t][0] = pk2(lrelu(d[0] + bv.x), lrelu(d[1] + bv.y));
      P[t][1] = pk2(lrelu(d[2] + bv.z), lrelu(d[3] + bv.w));
    }
    f32x4 D2[4] = {zero, zero, zero, zero};
#pragma unroll
    for (int kt = 0; kt < 4; ++kt) {
      unsigned u[4];
#pragma unroll
      for (int i = 0; i < 4; ++i) {
        const int srcidx = lo + 16 * (2 * (G & 1) + (i >> 1));
        unsigned r0 = (unsigned)__shfl((int)P[kt * 2][i & 1], srcidx);
        unsigned r1 = (unsigned)__shfl((int)P[kt * 2 + 1][i & 1], srcidx);
        u[i] = (lane >= 32) ? r1 : r0;
      }
      uint4 uu;
      uu.x = u[0]; uu.y = u[1]; uu.z = u[2]; uu.w = u[3];
      short8 B2 = __builtin_bit_cast(short8, uu);
#pragma unroll
      for (int ct = 0; ct < 4; ++ct) D2[ct] = MFMA16(A2[ct][kt], B2, D2[ct]);
    }
    unsigned short* row = (unsigned short*)xt + (size_t)(n0 + lo) * 64;
#pragma unroll
    for (int ct = 0; ct < 4; ++ct) {
      const float4 bv = *(const float4*)&b2n[ct * 16 + G * 4];
      uint2 s;
      s.x = pk2(D2[ct][0] + bv.x, D2[ct][1] + bv.y);
      s.y = pk2(D2[ct][2] + bv.z, D2[ct][3] + bv.w);
      *(uint2*)(row + ct * 16 + G * 4) = s;
    }
  }
}

// ============================================================================
// Fused edge pipeline: e_t = MLP(edge_attr) via MFMA (16 edges per wave),
// transpose msgs through per-wave LDS, then batched gather + packed atomics.
// ============================================================================
__global__ __launch_bounds__(256) void edge_mfma(const float* __restrict__ ea,
                                                 const int* __restrict__ ei,
                                                 const float* __restrict__ W1e,
                                                 const float* __restrict__ b1e,
                                                 const float* __restrict__ W2e,
                                                 const float* __restrict__ b2e,
                                                 const __hip_bfloat16* __restrict__ xt,
                                                 const float* __restrict__ dp,
                                                 float* __restrict__ agg) {
  const int lane = threadIdx.x & 63;
  const int lo = lane & 15;
  const int G = lane >> 4;
  const int w = threadIdx.x >> 6;
  const int wid = (blockIdx.x * blockDim.x + threadIdx.x) >> 6;
  const int nw = (gridDim.x * blockDim.x) >> 6;
  const float scale = dp[0];

  __shared__ float msg_lds[4][16 * 68];  // per-wave [16 edges][64+4 pad] f32
  float* ml = &msg_lds[w][0];

  short8 A1[4];
#pragma unroll
  for (int t = 0; t < 4; ++t) {
    float v[8];
#pragma unroll
    for (int j = 0; j < 8; ++j) v[j] = W1e[(G * 8 + j) * 64 + t * 16 + lo];
    A1[t] = mk_frag8(v);
  }
  short8 A2[4][2];
#pragma unroll
  for (int t = 0; t < 4; ++t)
#pragma unroll
    for (int kt = 0; kt < 2; ++kt) {
      float v[8];
#pragma unroll
      for (int j = 0; j < 8; ++j) v[j] = W2e[(kt * 32 + G * 8 + j) * 64 + t * 16 + lo];
      A2[t][kt] = mk_frag8(v);
    }
  f32x4 Cb1[4], Cb2[4];
#pragma unroll
  for (int t = 0; t < 4; ++t)
#pragma unroll
    for (int r = 0; r < 4; ++r) {
      Cb1[t][r] = b1e[t * 16 + G * 4 + r];
      Cb2[t][r] = b2e[t * 16 + G * 4 + r];
    }

  for (int tile = wid; tile < N_EDGES / 16; tile += nw) {
    const int e0 = tile * 16;
    const int srcv = ei[e0 + lo];
    const int dstv = ei[N_EDGES + e0 + lo];
    const float* p = &ea[(size_t)(e0 + lo) * 32 + G * 8];
    float4 q0 = *(const float4*)p;
    float4 q1 = *(const float4*)(p + 4);
    float v[8] = {q0.x, q0.y, q0.z, q0.w, q1.x, q1.y, q1.z, q1.w};
    short8 B1 = mk_frag8(v);

    unsigned P[4][2];
#pragma unroll
    for (int t = 0; t < 4; ++t) {
      f32x4 d = MFMA16(A1[t], B1, Cb1[t]);
      P[t][0] = pk2(lrelu(d[0]), lrelu(d[1]));
      P[t][1] = pk2(lrelu(d[2]), lrelu(d[3]));
    }
    short8 B2f[2];
#pragma unroll
    for (int kt = 0; kt < 2; ++kt) {
      unsigned u[4];
#pragma unroll
      for (int i = 0; i < 4; ++i) {
        const int srcidx = lo + 16 * (2 * (G & 1) + (i >> 1));
        unsigned r0 = (unsigned)__shfl((int)P[kt * 2][i & 1], srcidx);
        unsigned r1 = (unsigned)__shfl((int)P[kt * 2 + 1][i & 1], srcidx);
        u[i] = (lane >= 32) ? r1 : r0;
      }
      uint4 uu;
      uu.x = u[0]; uu.y = u[1]; uu.z = u[2]; uu.w = u[3];
      B2f[kt] = __builtin_bit_cast(short8, uu);
    }
    // e_t^T with dp_scale folded -> per-wave LDS (transpose buffer)
#pragma unroll
    for (int t = 0; t < 4; ++t) {
      f32x4 d = MFMA16(A2[t][0], B2f[0], Cb2[t]);
      d = MFMA16(A2[t][1], B2f[1], d);
      f32x4 sv;
#pragma unroll
      for (int r = 0; r < 4; ++r) sv[r] = d[r] * scale;
      *(f32x4*)&ml[lo * 68 + t * 16 + G * 4] = sv;
    }

#if HAVE_PK2_ATOMIC
    // wave covers 2 edges per instruction: lanes 0-31 -> edge 2ep, dims 2l..2l+1
    //                                      lanes 32-63 -> edge 2ep+1
    const int half = lane >> 5;
    const int l2 = lane & 31;
#pragma unroll
    for (int ep = 0; ep < 8; ++ep) {
      const int e = 2 * ep + half;  // per-lane edge index
      const int se = __shfl(srcv, e);
      const int de = __shfl(dstv, e);
      const float2 m = *(const float2*)&ml[e * 68 + 2 * l2];
      const unsigned g = *(const unsigned*)((const unsigned short*)xt + (size_t)se * 64 + 2 * l2);
      atomic_pk2(agg + (size_t)de * 64 + 2 * l2, blo(g) * m.x, bhi(g) * m.y);
    }
#else
    // fallback: whole wave per edge, gathers batched 8-deep before atomics
#pragma unroll
    for (int eb = 0; eb < 2; ++eb) {
      float msg[8];
      int des[8];
#pragma unroll
      for (int i = 0; i < 8; ++i) {
        const int e = eb * 8 + i;
        const int se = __builtin_amdgcn_readlane(srcv, e);
        des[i] = __builtin_amdgcn_readlane(dstv, e);
        const float m = ml[e * 68 + lane];
        const unsigned short xb = ((const unsigned short*)xt)[(size_t)se * 64 + lane];
        msg[i] = __uint_as_float((unsigned)xb << 16) * m;
      }
#pragma unroll
      for (int i = 0; i < 8; ++i)
        unsafeAtomicAdd(agg + (size_t)des[i] * 64 + lane, msg[i]);
    }
#endif
  }
}

// ---- residual + LayerNorm, in place on d_out (which holds the aggregate)
__global__ __launch_bounds__(256) void finalize(const float* __restrict__ x,
                                                const float* __restrict__ res_w,
                                                const float* __restrict__ gamma,
                                                const float* __restrict__ beta,
                                                float* __restrict__ out) {
  const int lane = threadIdx.x & 63;
  const int wid = (blockIdx.x * blockDim.x + threadIdx.x) >> 6;
  const int nw = (gridDim.x * blockDim.x) >> 6;
  const float rw = res_w[0];
  const float g = gamma[lane], bb = beta[lane];
  for (int n = wid; n < N_NODES; n += nw) {
    float v = fmaf(out[(size_t)n * 64 + lane], rw, x[(size_t)n * 64 + lane]);
    float s = v;
#pragma unroll
    for (int off = 1; off < 64; off <<= 1) s += __shfl_xor(s, off);
    const float mu = s * (1.f / 64.f);
    const float d = v - mu;
    float s2 = d * d;
#pragma unroll
    for (int off = 1; off < 64; off <<= 1) s2 += __shfl_xor(s2, off);
    out[(size_t)n * 64 + lane] = fmaf(d * rsqrtf(s2 * (1.f / 64.f) + EPS), g, bb);
  }
}

extern "C" void kernel_launch(void* const* d_in, const int* in_sizes, int n_in,
                              void* d_out, int out_size, void* d_ws, size_t ws_size,
                              hipStream_t stream) {
  const float* x = (const float*)d_in[0];
  const float* edge_attr = (const float*)d_in[1];
  const float* W1n = (const float*)d_in[2];
  const float* b1n = (const float*)d_in[3];
  const float* W2n = (const float*)d_in[4];
  const float* b2n = (const float*)d_in[5];
  const float* W1e = (const float*)d_in[6];
  const float* b1e = (const float*)d_in[7];
  const float* W2e = (const float*)d_in[8];
  const float* b2e = (const float*)d_in[9];
  const float* res_w = (const float*)d_in[10];
  const float* dp_scale = (const float*)d_in[11];
  const float* gamma = (const float*)d_in[12];
  const float* beta = (const float*)d_in[13];
  const int* edge_index = (const int*)d_in[14];
  float* out = (float*)d_out;

  __hip_bfloat16* xt = (__hip_bfloat16*)d_ws;  // N_NODES * 64 bf16 = 12.8 MB

  hipMemsetAsync(d_out, 0, (size_t)out_size * sizeof(float), stream);
  node_mfma<<<1024, 256, 0, stream>>>(x, W1n, b1n, W2n, b2n, xt);
  edge_mfma<<<2048, 256, 0, stream>>>(edge_attr, edge_index, W1e, b1e, W2e, b2e,
                                      xt, dp_scale, out);
  finalize<<<1024, 256, 0, stream>>>(x, res_w, gamma, beta, out);
}

// Round 5
// 165.980 us; speedup vs baseline: 1.6252x; 1.6252x over previous
//
#include <hip/hip_runtime.h>
#include <hip/hip_bf16.h>

#define N_NODES 100000
#define N_EDGES 1000000
#define EPS 1e-5f
#define SLOPE 0.1f

typedef __attribute__((ext_vector_type(8))) short short8;
typedef __attribute__((ext_vector_type(4))) float f32x4;

#define MFMA16(a, b, c) __builtin_amdgcn_mfma_f32_16x16x32_bf16(a, b, c, 0, 0, 0)

__device__ __forceinline__ float lrelu(float v) { return v > 0.f ? v : SLOPE * v; }

__device__ __forceinline__ unsigned short f2bf(float f) {
  __hip_bfloat16 h = __float2bfloat16(f);
  return __builtin_bit_cast(unsigned short, h);
}
__device__ __forceinline__ unsigned pk2(float lo, float hi) {
  return (unsigned)f2bf(lo) | ((unsigned)f2bf(hi) << 16);
}
__device__ __forceinline__ float blo(unsigned u) { return __uint_as_float(u << 16); }
__device__ __forceinline__ float bhi(unsigned u) { return __uint_as_float(u & 0xffff0000u); }

__device__ __forceinline__ short8 mk_frag8(const float v[8]) {
  uint4 u;
  u.x = pk2(v[0], v[1]);
  u.y = pk2(v[2], v[3]);
  u.z = pk2(v[4], v[5]);
  u.w = pk2(v[6], v[7]);
  return __builtin_bit_cast(short8, u);
}

#if __has_builtin(__builtin_amdgcn_global_atomic_fadd_v2bf16)
#define AGG_BF16 1
typedef __attribute__((ext_vector_type(2))) short bf16x2;
typedef __attribute__((address_space(1))) bf16x2 gbf16x2;
__device__ __forceinline__ void atomic_pk_bf16(void* p, unsigned packed) {
  __builtin_amdgcn_global_atomic_fadd_v2bf16((gbf16x2*)(unsigned long long)p,
                                             __builtin_bit_cast(bf16x2, packed));
}
#else
#define AGG_BF16 0
#endif

// ============================================================================
// Fused node MLP: x_t = (lrelu(x@W1n + b1n))@W2n + b2n, stored bf16 [N,64].
// ============================================================================
__global__ __launch_bounds__(256) void node_mfma(const float* __restrict__ x,
                                                 const float* __restrict__ W1n,
                                                 const float* __restrict__ b1n,
                                                 const float* __restrict__ W2n,
                                                 const float* __restrict__ b2n,
                                                 __hip_bfloat16* __restrict__ xt) {
  const int lane = threadIdx.x & 63;
  const int lo = lane & 15;
  const int G = lane >> 4;
  const int wid = (blockIdx.x * blockDim.x + threadIdx.x) >> 6;
  const int nw = (gridDim.x * blockDim.x) >> 6;

  short8 A1[8][2];
#pragma unroll
  for (int t = 0; t < 8; ++t)
#pragma unroll
    for (int kt = 0; kt < 2; ++kt) {
      float v[8];
#pragma unroll
      for (int j = 0; j < 8; ++j) v[j] = W1n[(kt * 32 + G * 8 + j) * 128 + t * 16 + lo];
      A1[t][kt] = mk_frag8(v);
    }
  short8 A2[4][4];
#pragma unroll
  for (int ct = 0; ct < 4; ++ct)
#pragma unroll
    for (int kt = 0; kt < 4; ++kt) {
      float v[8];
#pragma unroll
      for (int j = 0; j < 8; ++j) v[j] = W2n[(kt * 32 + G * 8 + j) * 64 + ct * 16 + lo];
      A2[ct][kt] = mk_frag8(v);
    }
  const f32x4 zero = {0.f, 0.f, 0.f, 0.f};

  for (int tile = wid; tile < N_NODES / 16; tile += nw) {
    const int n0 = tile * 16;
    short8 B1[2];
#pragma unroll
    for (int kt = 0; kt < 2; ++kt) {
      const float* p = &x[(size_t)(n0 + lo) * 64 + kt * 32 + G * 8];
      float4 q0 = *(const float4*)p;
      float4 q1 = *(const float4*)(p + 4);
      float v[8] = {q0.x, q0.y, q0.z, q0.w, q1.x, q1.y, q1.z, q1.w};
      B1[kt] = mk_frag8(v);
    }
    unsigned P[8][2];
#pragma unroll
    for (int t = 0; t < 8; ++t) {
      f32x4 d = MFMA16(A1[t][0], B1[0], zero);
      d = MFMA16(A1[t][1], B1[1], d);
      const float4 bv = *(const float4*)&b1n[t * 16 + G * 4];
      P[t][0] = pk2(lrelu(d[0] + bv.x), lrelu(d[1] + bv.y));
      P[t][1] = pk2(lrelu(d[2] + bv.z), lrelu(d[3] + bv.w));
    }
    f32x4 D2[4] = {zero, zero, zero, zero};
#pragma unroll
    for (int kt = 0; kt < 4; ++kt) {
      unsigned u[4];
#pragma unroll
      for (int i = 0; i < 4; ++i) {
        const int srcidx = lo + 16 * (2 * (G & 1) + (i >> 1));
        unsigned r0 = (unsigned)__shfl((int)P[kt * 2][i & 1], srcidx);
        unsigned r1 = (unsigned)__shfl((int)P[kt * 2 + 1][i & 1], srcidx);
        u[i] = (lane >= 32) ? r1 : r0;
      }
      uint4 uu;
      uu.x = u[0]; uu.y = u[1]; uu.z = u[2]; uu.w = u[3];
      short8 B2 = __builtin_bit_cast(short8, uu);
#pragma unroll
      for (int ct = 0; ct < 4; ++ct) D2[ct] = MFMA16(A2[ct][kt], B2, D2[ct]);
    }
    unsigned short* row = (unsigned short*)xt + (size_t)(n0 + lo) * 64;
#pragma unroll
    for (int ct = 0; ct < 4; ++ct) {
      const float4 bv = *(const float4*)&b2n[ct * 16 + G * 4];
      uint2 s;
      s.x = pk2(D2[ct][0] + bv.x, D2[ct][1] + bv.y);
      s.y = pk2(D2[ct][2] + bv.z, D2[ct][3] + bv.w);
      *(uint2*)(row + ct * 16 + G * 4) = s;
    }
  }
}

// ============================================================================
// Fused edge pipeline: e_t = MLP(edge_attr) via MFMA (16 edges per wave),
// transpose msgs through per-wave LDS, then gather + packed-bf16 atomics
// (128B atomic footprint per edge = 2 cache lines instead of 4).
// ============================================================================
__global__ __launch_bounds__(256) void edge_mfma(const float* __restrict__ ea,
                                                 const int* __restrict__ ei,
                                                 const float* __restrict__ W1e,
                                                 const float* __restrict__ b1e,
                                                 const float* __restrict__ W2e,
                                                 const float* __restrict__ b2e,
                                                 const __hip_bfloat16* __restrict__ xt,
                                                 const float* __restrict__ dp,
                                                 void* __restrict__ aggv) {
  const int lane = threadIdx.x & 63;
  const int lo = lane & 15;
  const int G = lane >> 4;
  const int w = threadIdx.x >> 6;
  const int wid = (blockIdx.x * blockDim.x + threadIdx.x) >> 6;
  const int nw = (gridDim.x * blockDim.x) >> 6;
  const float scale = dp[0];

  __shared__ float msg_lds[4][16 * 68];  // per-wave [16 edges][64+4 pad] f32
  float* ml = &msg_lds[w][0];

  short8 A1[4];
#pragma unroll
  for (int t = 0; t < 4; ++t) {
    float v[8];
#pragma unroll
    for (int j = 0; j < 8; ++j) v[j] = W1e[(G * 8 + j) * 64 + t * 16 + lo];
    A1[t] = mk_frag8(v);
  }
  short8 A2[4][2];
#pragma unroll
  for (int t = 0; t < 4; ++t)
#pragma unroll
    for (int kt = 0; kt < 2; ++kt) {
      float v[8];
#pragma unroll
      for (int j = 0; j < 8; ++j) v[j] = W2e[(kt * 32 + G * 8 + j) * 64 + t * 16 + lo];
      A2[t][kt] = mk_frag8(v);
    }
  f32x4 Cb1[4], Cb2[4];
#pragma unroll
  for (int t = 0; t < 4; ++t)
#pragma unroll
    for (int r = 0; r < 4; ++r) {
      Cb1[t][r] = b1e[t * 16 + G * 4 + r];
      Cb2[t][r] = b2e[t * 16 + G * 4 + r];
    }

  for (int tile = wid; tile < N_EDGES / 16; tile += nw) {
    const int e0 = tile * 16;
    const int srcv = ei[e0 + lo];
    const int dstv = ei[N_EDGES + e0 + lo];
    const float* p = &ea[(size_t)(e0 + lo) * 32 + G * 8];
    float4 q0 = *(const float4*)p;
    float4 q1 = *(const float4*)(p + 4);
    float v[8] = {q0.x, q0.y, q0.z, q0.w, q1.x, q1.y, q1.z, q1.w};
    short8 B1 = mk_frag8(v);

    unsigned P[4][2];
#pragma unroll
    for (int t = 0; t < 4; ++t) {
      f32x4 d = MFMA16(A1[t], B1, Cb1[t]);
      P[t][0] = pk2(lrelu(d[0]), lrelu(d[1]));
      P[t][1] = pk2(lrelu(d[2]), lrelu(d[3]));
    }
    short8 B2f[2];
#pragma unroll
    for (int kt = 0; kt < 2; ++kt) {
      unsigned u[4];
#pragma unroll
      for (int i = 0; i < 4; ++i) {
        const int srcidx = lo + 16 * (2 * (G & 1) + (i >> 1));
        unsigned r0 = (unsigned)__shfl((int)P[kt * 2][i & 1], srcidx);
        unsigned r1 = (unsigned)__shfl((int)P[kt * 2 + 1][i & 1], srcidx);
        u[i] = (lane >= 32) ? r1 : r0;
      }
      uint4 uu;
      uu.x = u[0]; uu.y = u[1]; uu.z = u[2]; uu.w = u[3];
      B2f[kt] = __builtin_bit_cast(short8, uu);
    }
    // e_t^T with dp_scale folded -> per-wave LDS (transpose buffer)
#pragma unroll
    for (int t = 0; t < 4; ++t) {
      f32x4 d = MFMA16(A2[t][0], B2f[0], Cb2[t]);
      d = MFMA16(A2[t][1], B2f[1], d);
      f32x4 sv;
#pragma unroll
      for (int r = 0; r < 4; ++r) sv[r] = d[r] * scale;
      *(f32x4*)&ml[lo * 68 + t * 16 + G * 4] = sv;
    }

#if AGG_BF16
    // wave covers 2 edges per instruction: lanes 0-31 -> edge 2ep, lanes
    // 32-63 -> edge 2ep+1; each lane atomically adds packed bf16 dims 2l,2l+1
    const int half = lane >> 5;
    const int l2 = lane & 31;
    unsigned short* aggb = (unsigned short*)aggv;
#pragma unroll
    for (int ep = 0; ep < 8; ++ep) {
      const int e = 2 * ep + half;
      const int se = __shfl(srcv, e);
      const int de = __shfl(dstv, e);
      const float2 m = *(const float2*)&ml[e * 68 + 2 * l2];
      const unsigned g = *(const unsigned*)((const unsigned short*)xt + (size_t)se * 64 + 2 * l2);
      atomic_pk_bf16(aggb + (size_t)de * 64 + 2 * l2, pk2(blo(g) * m.x, bhi(g) * m.y));
    }
#else
    float* agg = (float*)aggv;
#pragma unroll
    for (int eb = 0; eb < 2; ++eb) {
      float msg[8];
      int des[8];
#pragma unroll
      for (int i = 0; i < 8; ++i) {
        const int e = eb * 8 + i;
        const int se = __builtin_amdgcn_readlane(srcv, e);
        des[i] = __builtin_amdgcn_readlane(dstv, e);
        const float m = ml[e * 68 + lane];
        const unsigned short xb = ((const unsigned short*)xt)[(size_t)se * 64 + lane];
        msg[i] = __uint_as_float((unsigned)xb << 16) * m;
      }
#pragma unroll
      for (int i = 0; i < 8; ++i)
        unsafeAtomicAdd(agg + (size_t)des[i] * 64 + lane, msg[i]);
    }
#endif
  }
}

// ---- residual + LayerNorm: out = LN(x + agg * res_w) * gamma + beta
__global__ __launch_bounds__(256) void finalize(const float* __restrict__ x,
                                                const void* __restrict__ aggv,
                                                const float* __restrict__ res_w,
                                                const float* __restrict__ gamma,
                                                const float* __restrict__ beta,
                                                float* __restrict__ out) {
  const int lane = threadIdx.x & 63;
  const int wid = (blockIdx.x * blockDim.x + threadIdx.x) >> 6;
  const int nw = (gridDim.x * blockDim.x) >> 6;
  const float rw = res_w[0];
  const float g = gamma[lane], bb = beta[lane];
  for (int n = wid; n < N_NODES; n += nw) {
#if AGG_BF16
    const unsigned short ab = ((const unsigned short*)aggv)[(size_t)n * 64 + lane];
    const float a = __uint_as_float((unsigned)ab << 16);
#else
    const float a = ((const float*)aggv)[(size_t)n * 64 + lane];
#endif
    float v = fmaf(a, rw, x[(size_t)n * 64 + lane]);
    float s = v;
#pragma unroll
    for (int off = 1; off < 64; off <<= 1) s += __shfl_xor(s, off);
    const float mu = s * (1.f / 64.f);
    const float d = v - mu;
    float s2 = d * d;
#pragma unroll
    for (int off = 1; off < 64; off <<= 1) s2 += __shfl_xor(s2, off);
    out[(size_t)n * 64 + lane] = fmaf(d * rsqrtf(s2 * (1.f / 64.f) + EPS), g, bb);
  }
}

extern "C" void kernel_launch(void* const* d_in, const int* in_sizes, int n_in,
                              void* d_out, int out_size, void* d_ws, size_t ws_size,
                              hipStream_t stream) {
  const float* x = (const float*)d_in[0];
  const float* edge_attr = (const float*)d_in[1];
  const float* W1n = (const float*)d_in[2];
  const float* b1n = (const float*)d_in[3];
  const float* W2n = (const float*)d_in[4];
  const float* b2n = (const float*)d_in[5];
  const float* W1e = (const float*)d_in[6];
  const float* b1e = (const float*)d_in[7];
  const float* W2e = (const float*)d_in[8];
  const float* b2e = (const float*)d_in[9];
  const float* res_w = (const float*)d_in[10];
  const float* dp_scale = (const float*)d_in[11];
  const float* gamma = (const float*)d_in[12];
  const float* beta = (const float*)d_in[13];
  const int* edge_index = (const int*)d_in[14];
  float* out = (float*)d_out;

  __hip_bfloat16* xt = (__hip_bfloat16*)d_ws;            // N*64 bf16 = 12.8 MB
  void* agg = (void*)((char*)d_ws + (size_t)N_NODES * 64 * sizeof(__hip_bfloat16));
#if AGG_BF16
  const size_t agg_bytes = (size_t)N_NODES * 64 * sizeof(__hip_bfloat16);
#else
  const size_t agg_bytes = (size_t)N_NODES * 64 * sizeof(float);
#endif

  hipMemsetAsync(agg, 0, agg_bytes, stream);
  node_mfma<<<1024, 256, 0, stream>>>(x, W1n, b1n, W2n, b2n, xt);
  edge_mfma<<<2048, 256, 0, stream>>>(edge_attr, edge_index, W1e, b1e, W2e, b2e,
                                      xt, dp_scale, agg);
  finalize<<<1024, 256, 0, stream>>>(x, agg, res_w, gamma, beta, out);
}

// Round 6
// 155.008 us; speedup vs baseline: 1.7403x; 1.0708x over previous
//
#include <hip/hip_runtime.h>
#include <hip/hip_bf16.h>

#define N_NODES 100000
#define N_EDGES 1000000
#define EPS 1e-5f
#define SLOPE 0.1f

typedef __attribute__((ext_vector_type(8))) short short8;
typedef __attribute__((ext_vector_type(4))) float f32x4;

#define MFMA16(a, b, c) __builtin_amdgcn_mfma_f32_16x16x32_bf16(a, b, c, 0, 0, 0)

__device__ __forceinline__ float lrelu(float v) { return v > 0.f ? v : SLOPE * v; }

__device__ __forceinline__ unsigned short f2bf(float f) {
  __hip_bfloat16 h = __float2bfloat16(f);
  return __builtin_bit_cast(unsigned short, h);
}
__device__ __forceinline__ unsigned pk2(float lo, float hi) {
  return (unsigned)f2bf(lo) | ((unsigned)f2bf(hi) << 16);
}
__device__ __forceinline__ float blo(unsigned u) { return __uint_as_float(u << 16); }
__device__ __forceinline__ float bhi(unsigned u) { return __uint_as_float(u & 0xffff0000u); }

__device__ __forceinline__ short8 mk_frag8(const float v[8]) {
  uint4 u;
  u.x = pk2(v[0], v[1]);
  u.y = pk2(v[2], v[3]);
  u.z = pk2(v[4], v[5]);
  u.w = pk2(v[6], v[7]);
  return __builtin_bit_cast(short8, u);
}

#if __has_builtin(__builtin_amdgcn_global_atomic_fadd_v2bf16)
#define AGG_BF16 1
typedef __attribute__((ext_vector_type(2))) short bf16x2;
typedef __attribute__((address_space(1))) bf16x2 gbf16x2;
__device__ __forceinline__ void atomic_pk_bf16(void* p, unsigned packed) {
  __builtin_amdgcn_global_atomic_fadd_v2bf16((gbf16x2*)(unsigned long long)p,
                                             __builtin_bit_cast(bf16x2, packed));
}
#else
#define AGG_BF16 0
#endif

// ============================================================================
// Fused node MLP: x_t = (lrelu(x@W1n + b1n))@W2n + b2n, stored bf16 [N,64].
// Also zero-fills the aggregate buffer (replaces a separate memset dispatch).
// ============================================================================
__global__ __launch_bounds__(256) void node_mfma(const float* __restrict__ x,
                                                 const float* __restrict__ W1n,
                                                 const float* __restrict__ b1n,
                                                 const float* __restrict__ W2n,
                                                 const float* __restrict__ b2n,
                                                 __hip_bfloat16* __restrict__ xt,
                                                 uint4* __restrict__ agg_zero,
                                                 int agg_zero_n) {
  const int lane = threadIdx.x & 63;
  const int lo = lane & 15;
  const int G = lane >> 4;
  const int tid = blockIdx.x * blockDim.x + threadIdx.x;
  const int nt = gridDim.x * blockDim.x;
  const int wid = tid >> 6;
  const int nw = nt >> 6;

  // zero the aggregate buffer (independent streaming stores)
  const uint4 z = {0u, 0u, 0u, 0u};
  for (int i = tid; i < agg_zero_n; i += nt) agg_zero[i] = z;

  short8 A1[8][2];
#pragma unroll
  for (int t = 0; t < 8; ++t)
#pragma unroll
    for (int kt = 0; kt < 2; ++kt) {
      float v[8];
#pragma unroll
      for (int j = 0; j < 8; ++j) v[j] = W1n[(kt * 32 + G * 8 + j) * 128 + t * 16 + lo];
      A1[t][kt] = mk_frag8(v);
    }
  short8 A2[4][4];
#pragma unroll
  for (int ct = 0; ct < 4; ++ct)
#pragma unroll
    for (int kt = 0; kt < 4; ++kt) {
      float v[8];
#pragma unroll
      for (int j = 0; j < 8; ++j) v[j] = W2n[(kt * 32 + G * 8 + j) * 64 + ct * 16 + lo];
      A2[ct][kt] = mk_frag8(v);
    }
  const f32x4 zero = {0.f, 0.f, 0.f, 0.f};

  for (int tile = wid; tile < N_NODES / 16; tile += nw) {
    const int n0 = tile * 16;
    short8 B1[2];
#pragma unroll
    for (int kt = 0; kt < 2; ++kt) {
      const float* p = &x[(size_t)(n0 + lo) * 64 + kt * 32 + G * 8];
      float4 q0 = *(const float4*)p;
      float4 q1 = *(const float4*)(p + 4);
      float v[8] = {q0.x, q0.y, q0.z, q0.w, q1.x, q1.y, q1.z, q1.w};
      B1[kt] = mk_frag8(v);
    }
    unsigned P[8][2];
#pragma unroll
    for (int t = 0; t < 8; ++t) {
      f32x4 d = MFMA16(A1[t][0], B1[0], zero);
      d = MFMA16(A1[t][1], B1[1], d);
      const float4 bv = *(const float4*)&b1n[t * 16 + G * 4];
      P[t][0] = pk2(lrelu(d[0] + bv.x), lrelu(d[1] + bv.y));
      P[t][1] = pk2(lrelu(d[2] + bv.z), lrelu(d[3] + bv.w));
    }
    f32x4 D2[4] = {zero, zero, zero, zero};
#pragma unroll
    for (int kt = 0; kt < 4; ++kt) {
      unsigned u[4];
#pragma unroll
      for (int i = 0; i < 4; ++i) {
        const int srcidx = lo + 16 * (2 * (G & 1) + (i >> 1));
        unsigned r0 = (unsigned)__shfl((int)P[kt * 2][i & 1], srcidx);
        unsigned r1 = (unsigned)__shfl((int)P[kt * 2 + 1][i & 1], srcidx);
        u[i] = (lane >= 32) ? r1 : r0;
      }
      uint4 uu;
      uu.x = u[0]; uu.y = u[1]; uu.z = u[2]; uu.w = u[3];
      short8 B2 = __builtin_bit_cast(short8, uu);
#pragma unroll
      for (int ct = 0; ct < 4; ++ct) D2[ct] = MFMA16(A2[ct][kt], B2, D2[ct]);
    }
    unsigned short* row = (unsigned short*)xt + (size_t)(n0 + lo) * 64;
#pragma unroll
    for (int ct = 0; ct < 4; ++ct) {
      const float4 bv = *(const float4*)&b2n[ct * 16 + G * 4];
      uint2 s;
      s.x = pk2(D2[ct][0] + bv.x, D2[ct][1] + bv.y);
      s.y = pk2(D2[ct][2] + bv.z, D2[ct][3] + bv.w);
      *(uint2*)(row + ct * 16 + G * 4) = s;
    }
  }
}

// ============================================================================
// Fused edge pipeline: index loads + xt gathers hoisted to tile start (hide
// latency under the MFMA MLP), e_t = MLP(edge_attr), LDS transpose, then
// packed-bf16 atomics from registers (2 cache lines per edge, the minimum).
// ============================================================================
__global__ __launch_bounds__(256) void edge_mfma(const float* __restrict__ ea,
                                                 const int* __restrict__ ei,
                                                 const float* __restrict__ W1e,
                                                 const float* __restrict__ b1e,
                                                 const float* __restrict__ W2e,
                                                 const float* __restrict__ b2e,
                                                 const __hip_bfloat16* __restrict__ xt,
                                                 const float* __restrict__ dp,
                                                 void* __restrict__ aggv) {
  const int lane = threadIdx.x & 63;
  const int lo = lane & 15;
  const int G = lane >> 4;
  const int w = threadIdx.x >> 6;
  const int wid = (blockIdx.x * blockDim.x + threadIdx.x) >> 6;
  const int nw = (gridDim.x * blockDim.x) >> 6;
  const float scale = dp[0];

  __shared__ float msg_lds[4][16 * 68];  // per-wave [16 edges][64+4 pad] f32
  float* ml = &msg_lds[w][0];

  short8 A1[4];
#pragma unroll
  for (int t = 0; t < 4; ++t) {
    float v[8];
#pragma unroll
    for (int j = 0; j < 8; ++j) v[j] = W1e[(G * 8 + j) * 64 + t * 16 + lo];
    A1[t] = mk_frag8(v);
  }
  short8 A2[4][2];
#pragma unroll
  for (int t = 0; t < 4; ++t)
#pragma unroll
    for (int kt = 0; kt < 2; ++kt) {
      float v[8];
#pragma unroll
      for (int j = 0; j < 8; ++j) v[j] = W2e[(kt * 32 + G * 8 + j) * 64 + t * 16 + lo];
      A2[t][kt] = mk_frag8(v);
    }
  f32x4 Cb1[4], Cb2[4];
#pragma unroll
  for (int t = 0; t < 4; ++t)
#pragma unroll
    for (int r = 0; r < 4; ++r) {
      Cb1[t][r] = b1e[t * 16 + G * 4 + r];
      Cb2[t][r] = b2e[t * 16 + G * 4 + r];
    }

#if AGG_BF16
  const int half = lane >> 5;  // lanes 0-31 -> even edge, 32-63 -> odd edge
  const int l2 = lane & 31;
  unsigned short* aggb = (unsigned short*)aggv;
#endif

  for (int tile = wid; tile < N_EDGES / 16; tile += nw) {
    const int e0 = tile * 16;

#if AGG_BF16
    // ---- hoisted: per-lane edge indices and xt gathers (independent of MLP)
    int se_r[8], de_r[8];
#pragma unroll
    for (int ep = 0; ep < 8; ++ep) {
      se_r[ep] = ei[e0 + 2 * ep + half];
      de_r[ep] = ei[N_EDGES + e0 + 2 * ep + half];
    }
    unsigned g_r[8];
#pragma unroll
    for (int ep = 0; ep < 8; ++ep)
      g_r[ep] = *(const unsigned*)((const unsigned short*)xt + (size_t)se_r[ep] * 64 + 2 * l2);
#else
    const int srcv = ei[e0 + lo];
    const int dstv = ei[N_EDGES + e0 + lo];
#endif

    // ---- MLP (MFMA) while gathers are in flight
    const float* p = &ea[(size_t)(e0 + lo) * 32 + G * 8];
    float4 q0 = *(const float4*)p;
    float4 q1 = *(const float4*)(p + 4);
    float v[8] = {q0.x, q0.y, q0.z, q0.w, q1.x, q1.y, q1.z, q1.w};
    short8 B1 = mk_frag8(v);

    unsigned P[4][2];
#pragma unroll
    for (int t = 0; t < 4; ++t) {
      f32x4 d = MFMA16(A1[t], B1, Cb1[t]);
      P[t][0] = pk2(lrelu(d[0]), lrelu(d[1]));
      P[t][1] = pk2(lrelu(d[2]), lrelu(d[3]));
    }
    short8 B2f[2];
#pragma unroll
    for (int kt = 0; kt < 2; ++kt) {
      unsigned u[4];
#pragma unroll
      for (int i = 0; i < 4; ++i) {
        const int srcidx = lo + 16 * (2 * (G & 1) + (i >> 1));
        unsigned r0 = (unsigned)__shfl((int)P[kt * 2][i & 1], srcidx);
        unsigned r1 = (unsigned)__shfl((int)P[kt * 2 + 1][i & 1], srcidx);
        u[i] = (lane >= 32) ? r1 : r0;
      }
      uint4 uu;
      uu.x = u[0]; uu.y = u[1]; uu.z = u[2]; uu.w = u[3];
      B2f[kt] = __builtin_bit_cast(short8, uu);
    }
    // e_t^T with dp_scale folded -> per-wave LDS (transpose buffer)
#pragma unroll
    for (int t = 0; t < 4; ++t) {
      f32x4 d = MFMA16(A2[t][0], B2f[0], Cb2[t]);
      d = MFMA16(A2[t][1], B2f[1], d);
      f32x4 sv;
#pragma unroll
      for (int r = 0; r < 4; ++r) sv[r] = d[r] * scale;
      *(f32x4*)&ml[lo * 68 + t * 16 + G * 4] = sv;
    }

#if AGG_BF16
    // ---- epilogue: pure LDS-read + register math + atomic (no global reads)
#pragma unroll
    for (int ep = 0; ep < 8; ++ep) {
      const int e = 2 * ep + half;
      const float2 m = *(const float2*)&ml[e * 68 + 2 * l2];
      const unsigned g = g_r[ep];
      atomic_pk_bf16(aggb + (size_t)de_r[ep] * 64 + 2 * l2, pk2(blo(g) * m.x, bhi(g) * m.y));
    }
#else
    float* agg = (float*)aggv;
#pragma unroll
    for (int eb = 0; eb < 2; ++eb) {
      float msg[8];
      int des[8];
#pragma unroll
      for (int i = 0; i < 8; ++i) {
        const int e = eb * 8 + i;
        const int se = __builtin_amdgcn_readlane(srcv, e);
        des[i] = __builtin_amdgcn_readlane(dstv, e);
        const float m = ml[e * 68 + lane];
        const unsigned short xb = ((const unsigned short*)xt)[(size_t)se * 64 + lane];
        msg[i] = __uint_as_float((unsigned)xb << 16) * m;
      }
#pragma unroll
      for (int i = 0; i < 8; ++i)
        unsafeAtomicAdd(agg + (size_t)des[i] * 64 + lane, msg[i]);
    }
#endif
  }
}

// ---- residual + LayerNorm: out = LN(x + agg * res_w) * gamma + beta
__global__ __launch_bounds__(256) void finalize(const float* __restrict__ x,
                                                const void* __restrict__ aggv,
                                                const float* __restrict__ res_w,
                                                const float* __restrict__ gamma,
                                                const float* __restrict__ beta,
                                                float* __restrict__ out) {
  const int lane = threadIdx.x & 63;
  const int wid = (blockIdx.x * blockDim.x + threadIdx.x) >> 6;
  const int nw = (gridDim.x * blockDim.x) >> 6;
  const float rw = res_w[0];
  const float g = gamma[lane], bb = beta[lane];
  for (int n = wid; n < N_NODES; n += nw) {
#if AGG_BF16
    const unsigned short ab = ((const unsigned short*)aggv)[(size_t)n * 64 + lane];
    const float a = __uint_as_float((unsigned)ab << 16);
#else
    const float a = ((const float*)aggv)[(size_t)n * 64 + lane];
#endif
    float v = fmaf(a, rw, x[(size_t)n * 64 + lane]);
    float s = v;
#pragma unroll
    for (int off = 1; off < 64; off <<= 1) s += __shfl_xor(s, off);
    const float mu = s * (1.f / 64.f);
    const float d = v - mu;
    float s2 = d * d;
#pragma unroll
    for (int off = 1; off < 64; off <<= 1) s2 += __shfl_xor(s2, off);
    out[(size_t)n * 64 + lane] = fmaf(d * rsqrtf(s2 * (1.f / 64.f) + EPS), g, bb);
  }
}

extern "C" void kernel_launch(void* const* d_in, const int* in_sizes, int n_in,
                              void* d_out, int out_size, void* d_ws, size_t ws_size,
                              hipStream_t stream) {
  const float* x = (const float*)d_in[0];
  const float* edge_attr = (const float*)d_in[1];
  const float* W1n = (const float*)d_in[2];
  const float* b1n = (const float*)d_in[3];
  const float* W2n = (const float*)d_in[4];
  const float* b2n = (const float*)d_in[5];
  const float* W1e = (const float*)d_in[6];
  const float* b1e = (const float*)d_in[7];
  const float* W2e = (const float*)d_in[8];
  const float* b2e = (const float*)d_in[9];
  const float* res_w = (const float*)d_in[10];
  const float* dp_scale = (const float*)d_in[11];
  const float* gamma = (const float*)d_in[12];
  const float* beta = (const float*)d_in[13];
  const int* edge_index = (const int*)d_in[14];
  float* out = (float*)d_out;

  __hip_bfloat16* xt = (__hip_bfloat16*)d_ws;            // N*64 bf16 = 12.8 MB
  void* agg = (void*)((char*)d_ws + (size_t)N_NODES * 64 * sizeof(__hip_bfloat16));
#if AGG_BF16
  const size_t agg_bytes = (size_t)N_NODES * 64 * sizeof(__hip_bfloat16);
#else
  const size_t agg_bytes = (size_t)N_NODES * 64 * sizeof(float);
#endif

  node_mfma<<<1024, 256, 0, stream>>>(x, W1n, b1n, W2n, b2n, xt,
                                      (uint4*)agg, (int)(agg_bytes / 16));
  edge_mfma<<<2048, 256, 0, stream>>>(edge_attr, edge_index, W1e, b1e, W2e, b2e,
                                      xt, dp_scale, agg);
  finalize<<<1024, 256, 0, stream>>>(x, agg, res_w, gamma, beta, out);
}